// Round 9
// baseline (516.867 us; speedup 1.0000x reference)
//
#include <hip/hip_runtime.h>
#include <stdint.h>

typedef _Float16 half8 __attribute__((ext_vector_type(8)));
typedef float floatx16 __attribute__((ext_vector_type(16)));
typedef unsigned long long u64;

#define ALPHA_ 1.0f
#define BETA_ 0.25f
#define NUM_EMBEDS 8192
#define EMBED_DIM 512
#define B_ 32
#define T_ 256
#define N_TOK 8192

// ---------------- ws layout (bytes) ----------------
// wexact   @ 0        (64 KB)  u64 packed exact min: monokey<<32 | code
// cnorm    @ 65536    (32 KB)  ||c||^2 (fp32 exact)
// counts   @ 98304    (32 KB)
// znorm    @ 131072   (32 KB)  ||z_tok||^2 (fp32)
// sse      @ 163840   (4 B)
// (unused) @ 163844   (4 B)
// maxC2    @ 163848   (4 B)   uint bits of max ||c||^2
// slot_m1  @ 1  MB    (4 MB)  u64 [64 chunks][8192 tok] chunk min1 key
// slot_d   @ 5  MB    (1 MB)  f16 [64][8192] (min2 - min1) delta
// cb_h     @ 6  MB    (8 MB)  f16 fragment-major codebook (single plane)
// zt_h     @ 14 MB    (8 MB)  f16 fragment-major -2*z^T (single plane)
// ---------------------------------------------------
// fragment-major (halves):
//   cb_h: [ctile32][slot(32)][lane(64)][8]          ctile stride 16384
//   zt_h: [tb128][slot(32)][q(4)][lane(64)][8]      tb stride 65536
// slot s covers d in [ (s>>1)*32 + (s&1)*16, +16 ) in both arrays.
// Single-plane numerics: |err(dot)| <= 2^-9 ||z|| maxC. Gap test THR = 2B +
// slack; flagged tokens exactly rescored over chunks with chunkmin <= g1+THR
// (provably sufficient: the true-argmin chunk always qualifies).

__device__ __forceinline__ uint32_t mono(float s) {
    uint32_t u = __float_as_uint(s);
    return (u & 0x80000000u) ? ~u : (u | 0x80000000u);
}
__device__ __forceinline__ float unmono(uint32_t v) {
    return __uint_as_float((v & 0x80000000u) ? (v ^ 0x80000000u) : ~v);
}

// ---- fused pack: blocks [0,2048) pack codebook, [2048,2560) pack z ----
__global__ void pack_kernel(const float* __restrict__ cb, const float* __restrict__ z,
                            _Float16* __restrict__ cf, _Float16* __restrict__ zf,
                            float* __restrict__ cnorm, unsigned int* __restrict__ maxC2,
                            float* __restrict__ znorm) {
    int tid = threadIdx.x;
    if (blockIdx.x < 2048) {
        int row = blockIdx.x * 4 + (tid >> 6);
        int l = tid & 63;
        const float* src = cb + (size_t)row * EMBED_DIM + l * 8;
        float4 v0 = *(const float4*)src;
        float4 v1 = *(const float4*)(src + 4);
        float x[8] = {v0.x, v0.y, v0.z, v0.w, v1.x, v1.y, v1.z, v1.w};
        half8 hh;
        float s = 0.f;
#pragma unroll
        for (int j = 0; j < 8; ++j) {
            s += x[j] * x[j];
            hh[j] = (_Float16)x[j];
        }
        int slot = (l >> 2) * 2 + ((l >> 1) & 1);
        int flane = (row & 31) + (l & 1) * 32;
        *(half8*)(cf + (size_t)(row >> 5) * 16384 + (size_t)slot * 512 + flane * 8) = hh;
#pragma unroll
        for (int d = 32; d; d >>= 1) s += __shfl_xor(s, d, 64);
        if (l == 0) {
            cnorm[row] = s;
            atomicMax(maxC2, __float_as_uint(s));
        }
    } else {
        int zb = blockIdx.x - 2048;       // 0..511
        int bx = zb & 127, g0 = (zb >> 7) * 4;
        int l = tid & 63, ds = tid >> 6;
        int n = bx * 64 + l;
        int b = n >> 8, t = n & 255;
        int kk = ds >> 1, hfb = ds & 1;
        int tb = n >> 7, q = (n >> 5) & 3;
        size_t lanebase = (size_t)tb * 65536 + (size_t)q * 512 +
                          (size_t)((n & 31) + hfb * 32) * 8;
        float zz = 0.f;
        for (int g = g0; g < g0 + 4; ++g) {
            int d0 = g * 32 + ds * 8;
            const float* src = z + ((size_t)b * EMBED_DIM + d0) * T_ + t;
            half8 hh;
#pragma unroll
            for (int j = 0; j < 8; ++j) {
                float zo = src[(size_t)j * T_];
                zz += zo * zo;
                hh[j] = (_Float16)(-2.0f * zo);
            }
            int slot = g * 2 + kk;
            *(half8*)(zf + lanebase + (size_t)slot * 2048) = hh;
        }
        atomicAdd(&znorm[n], zz);
    }
}

// ---- pass 1: single-plane f16 argmin GEMM, LDS-staged via reg round-trip
//      (plain HIP: global_load -> VGPR -> ds_write_b128; T14 issue-early /
//      write-late split). Block = 256 codes x 128 tokens, 4 waves, BK=32,
//      double-buffered LDS, one barrier per K-step, 2 blocks/CU. Each global
//      byte enters the CU once; operands re-read from LDS at 256B/cyc
//      (fixes the TA/L1 64B/cyc bottleneck of the R2-R6 global->reg design). ----
#define MFMA16(a, b, c) __builtin_amdgcn_mfma_f32_32x32x16_f16(a, b, c, 0, 0, 0)

__global__ __launch_bounds__(256, 2) void argmin_kernel(
    const _Float16* __restrict__ cb_h, const _Float16* __restrict__ zt_h,
    const float* __restrict__ cnorm, u64* __restrict__ slot_m1,
    _Float16* __restrict__ slot_d) {
    __shared__ alignas(16) _Float16 Sm[2][12288];  // [buf][A:16x512 | B:8x512] = 48KB
    const int tid = threadIdx.x;
    const int l = tid & 63;
    const int wv = tid >> 6;       // 0..3
    const int l31 = l & 31;
    const int hf = l >> 5;
    const int wm = wv >> 1;        // code half (128 codes)
    const int wn = wv & 1;         // token half (64 tokens)
    const int l8 = l * 8;

    // bijective XCD swizzle (2048 blocks, 2048%8==0)
    const int flat = blockIdx.y * gridDim.x + blockIdx.x;
    const int cpx = (gridDim.x * gridDim.y) >> 3;
    const int swz = (flat & 7) * cpx + (flat >> 3);
    const int tb = swz & 63;       // token block (128 tokens)
    const int cg = swz >> 6;       // code group (256 codes), 0..31
    const int c0 = cg * 256;

    const _Float16* Abase = cb_h + (size_t)(cg * 8) * 16384;
    const _Float16* Bbase = zt_h + (size_t)tb * 65536;

    floatx16 acc[4][2];
#pragma unroll
    for (int a = 0; a < 4; ++a)
#pragma unroll
        for (int q = 0; q < 2; ++q)
#pragma unroll
            for (int r = 0; r < 16; ++r) acc[a][q][r] = 0.f;

    // staging registers: wave wv owns A chunks j=4wv..4wv+3, B chunks jb=2wv..2wv+1
    half8 sa[4], sb[2];
    auto load_stage = [&](int t) {
#pragma unroll
        for (int i = 0; i < 4; ++i) {
            int j = wv * 4 + i;  // A chunk = ct*2+kk
            sa[i] = *(const half8*)(Abase + (size_t)(j >> 1) * 16384 +
                                    (size_t)(2 * t + (j & 1)) * 512 + l8);
        }
#pragma unroll
        for (int i = 0; i < 2; ++i) {
            int jb = wv * 2 + i;  // B chunk = kk*4+q
            sb[i] = *(const half8*)(Bbase + (size_t)(2 * t + (jb >> 2)) * 2048 +
                                    (size_t)(jb & 3) * 512 + l8);
        }
    };
    auto write_stage = [&](int p) {
        _Float16* dst = Sm[p];
#pragma unroll
        for (int i = 0; i < 4; ++i)
            *(half8*)(dst + (wv * 4 + i) * 512 + l8) = sa[i];
#pragma unroll
        for (int i = 0; i < 2; ++i)
            *(half8*)(dst + 8192 + (wv * 2 + i) * 512 + l8) = sb[i];
    };

    load_stage(0);
    write_stage(0);
    __syncthreads();
    for (int t = 0; t < 16; ++t) {
        const int p = t & 1;
        if (t < 15) load_stage(t + 1);  // issue global loads before compute
        const _Float16* Ab = Sm[p] + (size_t)(wm * 8) * 512;        // 4 ctiles x 2 kk
        const _Float16* Bb = Sm[p] + 8192 + (size_t)wn * 1024;      // + kk*2048 + q*512
#pragma unroll
        for (int kk = 0; kk < 2; ++kk) {
            half8 b0 = *(const half8*)(Bb + kk * 2048 + l8);
            half8 b1 = *(const half8*)(Bb + kk * 2048 + 512 + l8);
#pragma unroll
            for (int ti = 0; ti < 4; ++ti) {
                half8 a = *(const half8*)(Ab + (size_t)(ti * 2 + kk) * 512 + l8);
                acc[ti][0] = MFMA16(a, b0, acc[ti][0]);
                acc[ti][1] = MFMA16(a, b1, acc[ti][1]);
            }
        }
        if (t < 15) write_stage(p ^ 1);  // write-late: HBM latency hid under MFMAs
        __syncthreads();
    }

    // epilogue: wave covers chunk cid = cg*2+wm (128 codes) x 64 tokens (wn half)
    const int cb0 = c0 + wm * 128;
    const int cid = cg * 2 + wm;
#pragma unroll
    for (int q = 0; q < 2; ++q) {
        u64 m1k = ~0ULL;
        float m1v = 3.4e38f, m2 = 3.4e38f;
#pragma unroll
        for (int ti = 0; ti < 4; ++ti)
#pragma unroll
            for (int g = 0; g < 4; ++g) {
                const int cb4 = cb0 + ti * 32 + g * 8 + hf * 4;
                float4 cn = *(const float4*)(cnorm + cb4);
                float sv[4] = {cn.x + acc[ti][q][g * 4 + 0], cn.y + acc[ti][q][g * 4 + 1],
                               cn.z + acc[ti][q][g * 4 + 2], cn.w + acc[ti][q][g * 4 + 3]};
#pragma unroll
                for (int r = 0; r < 4; ++r) {
                    u64 key = ((u64)mono(sv[r]) << 32) | (uint32_t)(cb4 + r);
                    if (key < m1k) { m2 = m1v; m1v = sv[r]; m1k = key; }
                    else m2 = fminf(m2, sv[r]);
                }
            }
        u64 ok = __shfl_xor(m1k, 32, 64);
        float ov = __shfl_xor(m1v, 32, 64);
        float om2 = __shfl_xor(m2, 32, 64);
        if (ok < m1k) { m2 = fminf(fminf(m2, om2), m1v); m1v = ov; m1k = ok; }
        else m2 = fminf(fminf(m2, om2), ov);
        if (hf == 0) {
            int tok = tb * 128 + wn * 64 + q * 32 + l31;
            slot_m1[((size_t)cid << 13) + tok] = m1k;
            slot_d[((size_t)cid << 13) + tok] = (_Float16)(m2 - m1v);
        }
    }
}

// ---- fused combine+fallback: 16 tokens/block. Phase 1: 16 threads/token merge
//      64 chunk summaries + gap test; flagged tokens emit (tok,chunk) pairs to
//      LDS. Phase 2: one wave per pair rescores 128 codes exactly (fp32). ----
__global__ void combinefb_kernel(const u64* __restrict__ slot_m1, const _Float16* __restrict__ slot_d,
                                 const float* __restrict__ znorm, const unsigned int* __restrict__ maxC2,
                                 const float* __restrict__ z, const float* __restrict__ cb,
                                 const float* __restrict__ cnorm, u64* __restrict__ wexact) {
    __shared__ unsigned short sPair[1024];
    __shared__ int snp;
    __shared__ float zs[4][512];
    const int tid = threadIdx.x;
    if (tid == 0) snp = 0;
    __syncthreads();

    const int ti16 = tid >> 4, sub = tid & 15;
    const int tok = blockIdx.x * 16 + ti16;
    u64 g1 = ~0ULL;
    float g1v = 3.4e38f, g2 = 3.4e38f;
    for (int c = sub; c < 64; c += 16) {
        u64 k = slot_m1[((size_t)c << 13) + tok];
        float kv = unmono((uint32_t)(k >> 32));
        float v2 = kv + (float)slot_d[((size_t)c << 13) + tok];
        if (k < g1) { g2 = fminf(g2, g1v); g1 = k; g1v = kv; }
        else g2 = fminf(g2, kv);
        g2 = fminf(g2, v2);
    }
#pragma unroll
    for (int m = 1; m < 16; m <<= 1) {
        u64 ok = __shfl_xor(g1, m, 64);
        float ov = __shfl_xor(g1v, m, 64);
        float o2 = __shfl_xor(g2, m, 64);
        if (ok < g1) { g2 = fminf(fminf(g2, o2), g1v); g1 = ok; g1v = ov; }
        else g2 = fminf(fminf(g2, o2), ov);
    }
    float maxC = sqrtf(__uint_as_float(*maxC2));
    float thr = sqrtf(znorm[tok]) * maxC * (1.0f / 256.0f) + 0.15f;
    if (g2 - g1v > thr) {
        if (sub == 0) wexact[tok] = g1;
    } else {
        float cutv = g1v + thr;
        for (int c = sub; c < 64; c += 16) {
            u64 k = slot_m1[((size_t)c << 13) + tok];
            if (unmono((uint32_t)(k >> 32)) <= cutv) {
                int i = atomicAdd(&snp, 1);
                sPair[i] = (unsigned short)((ti16 << 6) | c);
            }
        }
    }
    __syncthreads();

    const int np = snp;
    const int l = tid & 63, wv = tid >> 6;
    for (int p = wv; p < np; p += 4) {
        int pk = sPair[p];
        int tk = blockIdx.x * 16 + (pk >> 6), cid = pk & 63;
        int b = tk >> 8, t = tk & 255;
        const float* zp = z + (size_t)b * EMBED_DIM * T_ + t;
        float zv[8];
#pragma unroll
        for (int j = 0; j < 8; ++j) zv[j] = zp[(size_t)(l * 8 + j) * T_];
        *(float4*)&zs[wv][l * 8] = make_float4(zv[0], zv[1], zv[2], zv[3]);
        *(float4*)&zs[wv][l * 8 + 4] = make_float4(zv[4], zv[5], zv[6], zv[7]);
        // same-wave produce->consume: compiler inserts lgkmcnt wait, no barrier
        u64 best = ~0ULL;
#pragma unroll
        for (int jj = 0; jj < 2; ++jj) {
            int code = cid * 128 + jj * 64 + l;
            const float* cp = cb + (size_t)code * EMBED_DIM;
            float acc = 0.f;
#pragma unroll 4
            for (int d = 0; d < 512; d += 4) {
                float4 cv = *(const float4*)(cp + d);
                float4 zq = *(const float4*)&zs[wv][d];
                acc += cv.x * zq.x + cv.y * zq.y + cv.z * zq.z + cv.w * zq.w;
            }
            float s = cnorm[code] - 2.0f * acc;
            u64 key = ((u64)mono(s) << 32) | (uint32_t)code;
            if (key < best) best = key;
        }
#pragma unroll
        for (int m = 32; m; m >>= 1) {
            u64 ok = __shfl_xor(best, m, 64);
            best = ok < best ? ok : best;
        }
        if (l == 0) atomicMin(&wexact[tk], best);
    }
}

// ---- gather: 32 tokens/block x 512 threads; lane = token, 16 d-groups of 32
//      consecutive d per lane ----
__global__ void gather_kernel(const float* __restrict__ z, const float* __restrict__ cb,
                              const u64* __restrict__ wexact,
                              float* __restrict__ out, int* __restrict__ counts,
                              float* __restrict__ sse_acc) {
    __shared__ unsigned int sIdx[32];
    __shared__ float red[16];
    const int tid = threadIdx.x;
    const int n0 = blockIdx.x * 32;
    const int b = n0 >> 8;
    const int t0 = n0 & 255;
    if (tid < 32) {
        unsigned int idx = (unsigned int)(wexact[n0 + tid] & 0xffffffffULL);
        sIdx[tid] = idx;
        atomicAdd(&counts[idx], 1);
    }
    __syncthreads();
    const int sg = tid >> 5;
    const int l32 = tid & 31;
    const float* crow = cb + (size_t)sIdx[l32] * EMBED_DIM;
    const size_t base = ((size_t)b * EMBED_DIM) * T_ + (size_t)(t0 + l32);
    float sse = 0.f;
    const int d0 = sg * 32;
#pragma unroll 8
    for (int i = 0; i < 32; ++i) {
        int d = d0 + i;
        float v = crow[d];
        size_t o = base + (size_t)d * T_;
        float diff = v - z[o];
        out[o] = v;
        sse += diff * diff;
    }
#pragma unroll
    for (int m = 16; m; m >>= 1) sse += __shfl_xor(sse, m, 64);
    if (l32 == 0) red[sg] = sse;
    __syncthreads();
    if (tid == 0) {
        float s = 0.f;
#pragma unroll
        for (int i = 0; i < 16; ++i) s += red[i];
        atomicAdd(sse_acc, s);
    }
}

__global__ void finalize_kernel(const int* __restrict__ counts,
                                const float* __restrict__ sse_acc,
                                float* __restrict__ out) {
    __shared__ float red[4];
    const int tid = threadIdx.x;
    float e = 0.f;
    for (int k = tid; k < NUM_EMBEDS; k += 256) {
        float p = (float)counts[k] * (1.0f / (float)N_TOK);
        e += p * logf(p + 1e-10f);
    }
    for (int m = 32; m; m >>= 1) e += __shfl_xor(e, m, 64);
    if ((tid & 63) == 0) red[tid >> 6] = e;
    __syncthreads();
    if (tid == 0) {
        float ent = red[0] + red[1] + red[2] + red[3];
        size_t off = (size_t)B_ * EMBED_DIM * T_;
        out[off + 0] = (ALPHA_ * BETA_) * sse_acc[0] / (float)((size_t)N_TOK * EMBED_DIM);
        out[off + 1] = expf(-ent);
    }
}

extern "C" void kernel_launch(void* const* d_in, const int* in_sizes, int n_in,
                              void* d_out, int out_size, void* d_ws, size_t ws_size,
                              hipStream_t stream) {
    const float* z = (const float*)d_in[0];
    const float* cb = (const float*)d_in[1];
    float* out = (float*)d_out;
    char* ws = (char*)d_ws;
    u64* wexact = (u64*)ws;
    float* cnorm = (float*)(ws + 65536);
    int* counts = (int*)(ws + 98304);
    float* znorm = (float*)(ws + 131072);
    float* sse = (float*)(ws + 163840);
    unsigned int* maxC2 = (unsigned int*)(ws + 163848);
    u64* slot_m1 = (u64*)(ws + (1ull << 20));
    _Float16* slot_d = (_Float16*)(ws + (5ull << 20));
    _Float16* cb_h = (_Float16*)(ws + (6ull << 20));
    _Float16* zt_h = (_Float16*)(ws + (14ull << 20));

    hipMemsetAsync(wexact, 0xFF, NUM_EMBEDS * sizeof(u64), stream);
    // counts (32K) + znorm (32K) + sse + pad + maxC2
    hipMemsetAsync(counts, 0, 65536 + 12, stream);

    pack_kernel<<<2560, 256, 0, stream>>>(cb, z, cb_h, zt_h, cnorm, maxC2, znorm);
    argmin_kernel<<<dim3(64, 32), 256, 0, stream>>>(cb_h, zt_h, cnorm, slot_m1, slot_d);
    combinefb_kernel<<<N_TOK / 16, 256, 0, stream>>>(slot_m1, slot_d, znorm, maxC2, z, cb, cnorm, wexact);
    gather_kernel<<<N_TOK / 32, 512, 0, stream>>>(z, cb, wexact, out, counts, sse);
    finalize_kernel<<<1, 256, 0, stream>>>(counts, sse, out);
}

// Round 10
// 384.961 us; speedup vs baseline: 1.3426x; 1.3426x over previous
//
#include <hip/hip_runtime.h>
#include <stdint.h>

typedef _Float16 half8 __attribute__((ext_vector_type(8)));
typedef float floatx16 __attribute__((ext_vector_type(16)));
typedef unsigned long long u64;

#define ALPHA_ 1.0f
#define BETA_ 0.25f
#define NUM_EMBEDS 8192
#define EMBED_DIM 512
#define B_ 32
#define T_ 256
#define N_TOK 8192
#define MAXPAIRS (1 << 20)

// ---------------- ws layout (bytes) ----------------
// wexact   @ 0        (64 KB)  u64 packed exact min: monokey<<32 | code
// cnorm    @ 65536    (32 KB)  ||c||^2 (fp32 exact)
// counts   @ 98304    (32 KB)
// znorm    @ 131072   (32 KB)  ||z_tok||^2 (fp32)
// sse      @ 163840   (4 B)
// npairs   @ 163844   (4 B)
// maxC2    @ 163848   (4 B)   uint bits of max ||c||^2
// slot_m1  @ 1  MB    (16 MB) u64 [256 groups][8192 tok] group min1 key
// slot_d   @ 17 MB    (4 MB)  f16 [256][8192] (min2 - min1) delta
// cb_h     @ 21 MB    (8 MB)  f16 fragment-major codebook (single plane)
// zt_h     @ 29 MB    (8 MB)  f16 fragment-major -2*z^T (single plane)
// pairs    @ 37 MB    (4 MB)  int (tok<<8)|gid rescore worklist
// ---------------------------------------------------
// fragment-major (halves):
//   cb_h: [ctile32][slot(32)][lane(64)][8]          ctile stride 16384
//   zt_h: [tb128][slot(32)][q(4)][lane(64)][8]      tb stride 65536
// Rescore granularity = 32-code groups (256 of them): the argmin epilogue's
// natural per-accumulator tile. Gap test THR = 2B + slack over group
// summaries; flagged tokens exactly rescored over groups with groupmin <=
// g1+THR (provably sufficient: the true-argmin group always qualifies).

__device__ __forceinline__ uint32_t mono(float s) {
    uint32_t u = __float_as_uint(s);
    return (u & 0x80000000u) ? ~u : (u | 0x80000000u);
}
__device__ __forceinline__ float unmono(uint32_t v) {
    return __uint_as_float((v & 0x80000000u) ? (v ^ 0x80000000u) : ~v);
}

// ---- fused pack: blocks [0,2048) pack codebook, [2048,2560) pack z ----
__global__ void pack_kernel(const float* __restrict__ cb, const float* __restrict__ z,
                            _Float16* __restrict__ cf, _Float16* __restrict__ zf,
                            float* __restrict__ cnorm, unsigned int* __restrict__ maxC2,
                            float* __restrict__ znorm) {
    int tid = threadIdx.x;
    if (blockIdx.x < 2048) {
        int row = blockIdx.x * 4 + (tid >> 6);
        int l = tid & 63;
        const float* src = cb + (size_t)row * EMBED_DIM + l * 8;
        float4 v0 = *(const float4*)src;
        float4 v1 = *(const float4*)(src + 4);
        float x[8] = {v0.x, v0.y, v0.z, v0.w, v1.x, v1.y, v1.z, v1.w};
        half8 hh;
        float s = 0.f;
#pragma unroll
        for (int j = 0; j < 8; ++j) {
            s += x[j] * x[j];
            hh[j] = (_Float16)x[j];
        }
        int slot = (l >> 2) * 2 + ((l >> 1) & 1);
        int flane = (row & 31) + (l & 1) * 32;
        *(half8*)(cf + (size_t)(row >> 5) * 16384 + (size_t)slot * 512 + flane * 8) = hh;
#pragma unroll
        for (int d = 32; d; d >>= 1) s += __shfl_xor(s, d, 64);
        if (l == 0) {
            cnorm[row] = s;
            atomicMax(maxC2, __float_as_uint(s));
        }
    } else {
        int zb = blockIdx.x - 2048;       // 0..511
        int bx = zb & 127, g0 = (zb >> 7) * 4;
        int l = tid & 63, ds = tid >> 6;
        int n = bx * 64 + l;
        int b = n >> 8, t = n & 255;
        int kk = ds >> 1, hfb = ds & 1;
        int tb = n >> 7, q = (n >> 5) & 3;
        size_t lanebase = (size_t)tb * 65536 + (size_t)q * 512 +
                          (size_t)((n & 31) + hfb * 32) * 8;
        float zz = 0.f;
        for (int g = g0; g < g0 + 4; ++g) {
            int d0 = g * 32 + ds * 8;
            const float* src = z + ((size_t)b * EMBED_DIM + d0) * T_ + t;
            half8 hh;
#pragma unroll
            for (int j = 0; j < 8; ++j) {
                float zo = src[(size_t)j * T_];
                zz += zo * zo;
                hh[j] = (_Float16)(-2.0f * zo);
            }
            int slot = g * 2 + kk;
            *(half8*)(zf + lanebase + (size_t)slot * 2048) = hh;
        }
        atomicAdd(&znorm[n], zz);
    }
}

// ---- pass 1: single-plane f16 argmin GEMM, LDS-staged via reg round-trip
//      (T14 issue-early / write-late). Block = 256 codes x 128 tokens, 4 waves,
//      BK=32, double-buffered LDS, one barrier per K-step, 2 blocks/CU.
//      Epilogue stores per-32-code-group summaries (4 groups/wave). ----
#define MFMA16(a, b, c) __builtin_amdgcn_mfma_f32_32x32x16_f16(a, b, c, 0, 0, 0)

__global__ __launch_bounds__(256, 2) void argmin_kernel(
    const _Float16* __restrict__ cb_h, const _Float16* __restrict__ zt_h,
    const float* __restrict__ cnorm, u64* __restrict__ slot_m1,
    _Float16* __restrict__ slot_d) {
    __shared__ alignas(16) _Float16 Sm[2][12288];  // [buf][A:16x512 | B:8x512] = 48KB
    const int tid = threadIdx.x;
    const int l = tid & 63;
    const int wv = tid >> 6;       // 0..3
    const int l31 = l & 31;
    const int hf = l >> 5;
    const int wm = wv >> 1;        // code half (128 codes)
    const int wn = wv & 1;         // token half (64 tokens)
    const int l8 = l * 8;

    // bijective XCD swizzle (2048 blocks, 2048%8==0)
    const int flat = blockIdx.y * gridDim.x + blockIdx.x;
    const int cpx = (gridDim.x * gridDim.y) >> 3;
    const int swz = (flat & 7) * cpx + (flat >> 3);
    const int tb = swz & 63;       // token block (128 tokens)
    const int cg = swz >> 6;       // code group (256 codes), 0..31
    const int c0 = cg * 256;

    const _Float16* Abase = cb_h + (size_t)(cg * 8) * 16384;
    const _Float16* Bbase = zt_h + (size_t)tb * 65536;

    floatx16 acc[4][2];
#pragma unroll
    for (int a = 0; a < 4; ++a)
#pragma unroll
        for (int q = 0; q < 2; ++q)
#pragma unroll
            for (int r = 0; r < 16; ++r) acc[a][q][r] = 0.f;

    // staging registers: wave wv owns A chunks j=4wv..4wv+3, B chunks jb=2wv..2wv+1
    half8 sa[4], sb[2];
    auto load_stage = [&](int t) {
#pragma unroll
        for (int i = 0; i < 4; ++i) {
            int j = wv * 4 + i;  // A chunk = ct*2+kk
            sa[i] = *(const half8*)(Abase + (size_t)(j >> 1) * 16384 +
                                    (size_t)(2 * t + (j & 1)) * 512 + l8);
        }
#pragma unroll
        for (int i = 0; i < 2; ++i) {
            int jb = wv * 2 + i;  // B chunk = kk*4+q
            sb[i] = *(const half8*)(Bbase + (size_t)(2 * t + (jb >> 2)) * 2048 +
                                    (size_t)(jb & 3) * 512 + l8);
        }
    };
    auto write_stage = [&](int p) {
        _Float16* dst = Sm[p];
#pragma unroll
        for (int i = 0; i < 4; ++i)
            *(half8*)(dst + (wv * 4 + i) * 512 + l8) = sa[i];
#pragma unroll
        for (int i = 0; i < 2; ++i)
            *(half8*)(dst + 8192 + (wv * 2 + i) * 512 + l8) = sb[i];
    };

    load_stage(0);
    write_stage(0);
    __syncthreads();
    for (int t = 0; t < 16; ++t) {
        const int p = t & 1;
        if (t < 15) load_stage(t + 1);  // issue global loads before compute
        const _Float16* Ab = Sm[p] + (size_t)(wm * 8) * 512;        // 4 ctiles x 2 kk
        const _Float16* Bb = Sm[p] + 8192 + (size_t)wn * 1024;      // + kk*2048 + q*512
#pragma unroll
        for (int kk = 0; kk < 2; ++kk) {
            half8 b0 = *(const half8*)(Bb + kk * 2048 + l8);
            half8 b1 = *(const half8*)(Bb + kk * 2048 + 512 + l8);
#pragma unroll
            for (int ti = 0; ti < 4; ++ti) {
                half8 a = *(const half8*)(Ab + (size_t)(ti * 2 + kk) * 512 + l8);
                acc[ti][0] = MFMA16(a, b0, acc[ti][0]);
                acc[ti][1] = MFMA16(a, b1, acc[ti][1]);
            }
        }
        if (t < 15) write_stage(p ^ 1);  // write-late: HBM latency hid under MFMAs
        __syncthreads();
    }

    // epilogue: per (q, ti) -> one 32-code group summary (gid = cg*8+wm*4+ti)
    const int cb0 = c0 + wm * 128;
    const int gid0 = cg * 8 + wm * 4;
#pragma unroll
    for (int q = 0; q < 2; ++q) {
#pragma unroll
        for (int ti = 0; ti < 4; ++ti) {
            u64 m1k = ~0ULL;
            float m1v = 3.4e38f, m2 = 3.4e38f;
#pragma unroll
            for (int g = 0; g < 4; ++g) {
                const int cb4 = cb0 + ti * 32 + g * 8 + hf * 4;
                float4 cn = *(const float4*)(cnorm + cb4);
                float sv[4] = {cn.x + acc[ti][q][g * 4 + 0], cn.y + acc[ti][q][g * 4 + 1],
                               cn.z + acc[ti][q][g * 4 + 2], cn.w + acc[ti][q][g * 4 + 3]};
#pragma unroll
                for (int r = 0; r < 4; ++r) {
                    u64 key = ((u64)mono(sv[r]) << 32) | (uint32_t)(cb4 + r);
                    if (key < m1k) { m2 = m1v; m1v = sv[r]; m1k = key; }
                    else m2 = fminf(m2, sv[r]);
                }
            }
            u64 ok = __shfl_xor(m1k, 32, 64);
            float ov = __shfl_xor(m1v, 32, 64);
            float om2 = __shfl_xor(m2, 32, 64);
            if (ok < m1k) { m2 = fminf(fminf(m2, om2), m1v); m1v = ov; m1k = ok; }
            else m2 = fminf(fminf(m2, om2), ov);
            if (hf == 0) {
                int tok = tb * 128 + wn * 64 + q * 32 + l31;
                slot_m1[((size_t)(gid0 + ti) << 13) + tok] = m1k;
                slot_d[((size_t)(gid0 + ti) << 13) + tok] = (_Float16)(m2 - m1v);
            }
        }
    }
}

// ---- combine: 16 threads/token merge 256 group summaries; deterministic-bound
//      gap test; emit (tok,group) pairs to a GLOBAL worklist (load balance) ----
__global__ void combine_kernel(const u64* __restrict__ slot_m1, const _Float16* __restrict__ slot_d,
                               const float* __restrict__ znorm, const unsigned int* __restrict__ maxC2,
                               u64* __restrict__ wexact, int* __restrict__ pairs,
                               int* __restrict__ npairs) {
    int tid = threadIdx.x;
    int tok = blockIdx.x * 16 + (tid >> 4);
    int sub = tid & 15;
    u64 g1 = ~0ULL;
    float g1v = 3.4e38f, g2 = 3.4e38f;
    for (int c = sub; c < 256; c += 16) {
        u64 k = slot_m1[((size_t)c << 13) + tok];
        float kv = unmono((uint32_t)(k >> 32));
        float v2 = kv + (float)slot_d[((size_t)c << 13) + tok];
        if (k < g1) { g2 = fminf(g2, g1v); g1 = k; g1v = kv; }
        else g2 = fminf(g2, kv);
        g2 = fminf(g2, v2);
    }
    // xor-butterfly merge across the 16 sub-lanes (all lanes get the result)
#pragma unroll
    for (int m = 1; m < 16; m <<= 1) {
        u64 ok = __shfl_xor(g1, m, 64);
        float ov = __shfl_xor(g1v, m, 64);
        float o2 = __shfl_xor(g2, m, 64);
        if (ok < g1) { g2 = fminf(fminf(g2, o2), g1v); g1 = ok; g1v = ov; }
        else g2 = fminf(fminf(g2, o2), ov);
    }
    // deterministic error bound: B = 2^-9 ||z|| maxC ; THR = 2B + slack
    float maxC = sqrtf(__uint_as_float(*maxC2));
    float thr = sqrtf(znorm[tok]) * maxC * (1.0f / 256.0f) + 0.15f;
    if (g2 - g1v > thr) {
        if (sub == 0) wexact[tok] = g1;
    } else {
        float cutv = g1v + thr;
        for (int c = sub; c < 256; c += 16) {
            u64 k = slot_m1[((size_t)c << 13) + tok];
            if (unmono((uint32_t)(k >> 32)) <= cutv) {
                int i = atomicAdd(npairs, 1);
                if (i < MAXPAIRS) pairs[i] = (tok << 8) | c;
            }
        }
    }
}

// ---- fallback: exact fp32 rescore, one wave per (tok,group) pair via global
//      grid-stride worklist; 32 codes/pair, dims hf-split across lane halves;
//      z staged once per pair into a per-wave LDS strip ----
__global__ void fallback_kernel(const float* __restrict__ z, const float* __restrict__ cb,
                                const float* __restrict__ cnorm,
                                const int* __restrict__ pairs, const int* __restrict__ npairs,
                                u64* __restrict__ wexact) {
    __shared__ float zs[4][512];
    int n = *npairs;
    if (n > MAXPAIRS) n = MAXPAIRS;
    const int l = threadIdx.x & 63, wv = threadIdx.x >> 6;
    const int l31 = l & 31, hf = l >> 5;
    int wid = blockIdx.x * 4 + wv;
    const int wstride = gridDim.x * 4;
    for (int pi = wid; pi < n; pi += wstride) {
        int pk = pairs[pi];
        int tok = pk >> 8, gid = pk & 255;
        int b = tok >> 8, t = tok & 255;
        const float* zp = z + (size_t)b * EMBED_DIM * T_ + t;
        float zv[8];
#pragma unroll
        for (int j = 0; j < 8; ++j) zv[j] = zp[(size_t)(l * 8 + j) * T_];
        *(float4*)&zs[wv][l * 8] = make_float4(zv[0], zv[1], zv[2], zv[3]);
        *(float4*)&zs[wv][l * 8 + 4] = make_float4(zv[4], zv[5], zv[6], zv[7]);
        // same-wave produce->consume: compiler inserts lgkmcnt wait, no barrier
        int code = gid * 32 + l31;
        const float* cp = cb + (size_t)code * EMBED_DIM + hf * 256;
        float acc = 0.f;
#pragma unroll 4
        for (int d = 0; d < 256; d += 4) {
            float4 cv = *(const float4*)(cp + d);
            float4 zq = *(const float4*)&zs[wv][hf * 256 + d];
            acc += cv.x * zq.x + cv.y * zq.y + cv.z * zq.z + cv.w * zq.w;
        }
        acc += __shfl_xor(acc, 32, 64);  // join the two dim-halves
        float s = cnorm[code] - 2.0f * acc;
        u64 key = ((u64)mono(s) << 32) | (uint32_t)code;
#pragma unroll
        for (int m = 16; m; m >>= 1) {
            u64 ok = __shfl_xor(key, m, 64);
            key = ok < key ? ok : key;
        }
        if (l == 0) atomicMin(&wexact[tok], key);
    }
}

// ---- gather: 32 tokens/block x 512 threads; lane = token, 16 d-groups of 32
//      consecutive d per lane ----
__global__ void gather_kernel(const float* __restrict__ z, const float* __restrict__ cb,
                              const u64* __restrict__ wexact,
                              float* __restrict__ out, int* __restrict__ counts,
                              float* __restrict__ sse_acc) {
    __shared__ unsigned int sIdx[32];
    __shared__ float red[16];
    const int tid = threadIdx.x;
    const int n0 = blockIdx.x * 32;
    const int b = n0 >> 8;
    const int t0 = n0 & 255;
    if (tid < 32) {
        unsigned int idx = (unsigned int)(wexact[n0 + tid] & 0xffffffffULL);
        sIdx[tid] = idx;
        atomicAdd(&counts[idx], 1);
    }
    __syncthreads();
    const int sg = tid >> 5;
    const int l32 = tid & 31;
    const float* crow = cb + (size_t)sIdx[l32] * EMBED_DIM;
    const size_t base = ((size_t)b * EMBED_DIM) * T_ + (size_t)(t0 + l32);
    float sse = 0.f;
    const int d0 = sg * 32;
#pragma unroll 8
    for (int i = 0; i < 32; ++i) {
        int d = d0 + i;
        float v = crow[d];
        size_t o = base + (size_t)d * T_;
        float diff = v - z[o];
        out[o] = v;
        sse += diff * diff;
    }
#pragma unroll
    for (int m = 16; m; m >>= 1) sse += __shfl_xor(sse, m, 64);
    if (l32 == 0) red[sg] = sse;
    __syncthreads();
    if (tid == 0) {
        float s = 0.f;
#pragma unroll
        for (int i = 0; i < 16; ++i) s += red[i];
        atomicAdd(sse_acc, s);
    }
}

__global__ void finalize_kernel(const int* __restrict__ counts,
                                const float* __restrict__ sse_acc,
                                float* __restrict__ out) {
    __shared__ float red[4];
    const int tid = threadIdx.x;
    float e = 0.f;
    for (int k = tid; k < NUM_EMBEDS; k += 256) {
        float p = (float)counts[k] * (1.0f / (float)N_TOK);
        e += p * logf(p + 1e-10f);
    }
    for (int m = 32; m; m >>= 1) e += __shfl_xor(e, m, 64);
    if ((tid & 63) == 0) red[tid >> 6] = e;
    __syncthreads();
    if (tid == 0) {
        float ent = red[0] + red[1] + red[2] + red[3];
        size_t off = (size_t)B_ * EMBED_DIM * T_;
        out[off + 0] = (ALPHA_ * BETA_) * sse_acc[0] / (float)((size_t)N_TOK * EMBED_DIM);
        out[off + 1] = expf(-ent);
    }
}

extern "C" void kernel_launch(void* const* d_in, const int* in_sizes, int n_in,
                              void* d_out, int out_size, void* d_ws, size_t ws_size,
                              hipStream_t stream) {
    const float* z = (const float*)d_in[0];
    const float* cb = (const float*)d_in[1];
    float* out = (float*)d_out;
    char* ws = (char*)d_ws;
    u64* wexact = (u64*)ws;
    float* cnorm = (float*)(ws + 65536);
    int* counts = (int*)(ws + 98304);
    float* znorm = (float*)(ws + 131072);
    float* sse = (float*)(ws + 163840);
    int* npairs = (int*)(ws + 163844);
    unsigned int* maxC2 = (unsigned int*)(ws + 163848);
    u64* slot_m1 = (u64*)(ws + (1ull << 20));
    _Float16* slot_d = (_Float16*)(ws + (17ull << 20));
    _Float16* cb_h = (_Float16*)(ws + (21ull << 20));
    _Float16* zt_h = (_Float16*)(ws + (29ull << 20));
    int* pairs = (int*)(ws + (37ull << 20));

    hipMemsetAsync(wexact, 0xFF, NUM_EMBEDS * sizeof(u64), stream);
    // counts (32K) + znorm (32K) + sse + npairs + maxC2
    hipMemsetAsync(counts, 0, 65536 + 12, stream);

    pack_kernel<<<2560, 256, 0, stream>>>(cb, z, cb_h, zt_h, cnorm, maxC2, znorm);
    argmin_kernel<<<dim3(64, 32), 256, 0, stream>>>(cb_h, zt_h, cnorm, slot_m1, slot_d);
    combine_kernel<<<N_TOK / 16, 256, 0, stream>>>(slot_m1, slot_d, znorm, maxC2, wexact, pairs, npairs);
    fallback_kernel<<<512, 256, 0, stream>>>(z, cb, cnorm, pairs, npairs, wexact);
    gather_kernel<<<N_TOK / 32, 512, 0, stream>>>(z, cb, wexact, out, counts, sse);
    finalize_kernel<<<1, 256, 0, stream>>>(counts, sse, out);
}